// Round 1
// baseline (498.287 us; speedup 1.0000x reference)
//
#include <hip/hip_runtime.h>
#include <stdint.h>

// ---------------------------------------------------------------------------
// MeshGraphNets edge processor on MI355X:
//   gather(sender,receiver) + concat(edge) -> 384->128 relu -> 128->128 relu
//   -> 128->128 -> LayerNorm.  E=320000, all fp32 in/out.
//
// No fp32 MFMA on CDNA4 -> split-bf16: x = hi + lo (both bf16), accumulate
// hi*Bhi + lo*Bhi + hi*Blo in fp32 AGPRs (error ~2^-17, fp32-check safe).
// Block: 512 thr (8 waves) x 128 edges; wave owns 16 rows x 128 cols.
// Weights pre-split/transposed into d_ws; staged per-64-K slab into
// double-buffered, XOR-swizzled LDS (conflict-free ds_read_b128).
// ---------------------------------------------------------------------------

typedef __attribute__((ext_vector_type(8))) short   s16x8;
typedef __attribute__((ext_vector_type(8))) __bf16  bf16x8;
typedef __attribute__((ext_vector_type(4))) float   f32x4;
typedef __attribute__((ext_vector_type(4))) int     i32x4;

__device__ __forceinline__ unsigned rne_bf16(float x) {
  unsigned u = __builtin_bit_cast(unsigned, x);
  return (u + 0x7fffu + ((u >> 16) & 1u)) >> 16;
}

__device__ __forceinline__ f32x4 mfma_bf16(s16x8 a, s16x8 b, f32x4 c) {
  return __builtin_amdgcn_mfma_f32_16x16x32_bf16(
      __builtin_bit_cast(bf16x8, a), __builtin_bit_cast(bf16x8, b), c, 0, 0, 0);
}

__device__ __forceinline__ void split8(float4 a, float4 b, s16x8 &hi, s16x8 &lo) {
  float v[8] = {a.x, a.y, a.z, a.w, b.x, b.y, b.z, b.w};
#pragma unroll
  for (int j = 0; j < 8; ++j) {
    unsigned hb = rne_bf16(v[j]);
    float fh = __builtin_bit_cast(float, hb << 16);
    unsigned lb = rne_bf16(v[j] - fh);
    hi[j] = (short)hb;
    lo[j] = (short)lb;
  }
}

// Stage one 64-wide K-slab of a [128][K] bf16 hi/lo plane pair into a 32 KiB
// LDS buffer. 16B-chunk XOR swizzle (kcol ^= n&7) kills the 128B-row-stride
// bank conflict on the B-fragment ds_read_b128s.
__device__ __forceinline__ void stage_slab(const short *__restrict__ base,
                                           int planeElems, int K, int slab,
                                           char *sB, int tid) {
#pragma unroll
  for (int i = 0; i < 4; ++i) {
    int c   = tid + i * 512;        // 2048 chunks of 16B = 32 KiB
    int p   = c >> 10;              // plane: 0=hi 1=lo
    int c10 = c & 1023;
    int n   = c10 >> 3;             // output-latent row 0..127
    int kc  = c10 & 7;              // 16B chunk within 64-k slab
    i32x4 v = *(const i32x4 *)(base + p * planeElems + n * K + slab * 64 + kc * 8);
    *(i32x4 *)(sB + p * 16384 + n * 128 + ((kc ^ (n & 7)) << 4)) = v;
  }
}

// One K=32 MFMA step across all 8 N-tiles: acc += Ahi*Bhi + Alo*Bhi + Ahi*Blo
__device__ __forceinline__ void do_kstep(const char *sB, int kc, int lr,
                                         s16x8 ah, s16x8 al, f32x4 (&acc)[8]) {
#pragma unroll
  for (int nt = 0; nt < 8; ++nt) {
    int n    = nt * 16 + lr;
    int boff = n * 128 + ((kc ^ (n & 7)) << 4);
    s16x8 bh = *(const s16x8 *)(sB + boff);
    s16x8 bl = *(const s16x8 *)(sB + 16384 + boff);
    acc[nt] = mfma_bf16(ah, bh, acc[nt]);
    acc[nt] = mfma_bf16(al, bh, acc[nt]);
    acc[nt] = mfma_bf16(ah, bl, acc[nt]);
  }
}

// bias + relu + hi/lo split; transpose C-layout (col=lane&15,row=lg*4+j) into
// A-layout [row][k] in the wave-private swizzled LDS region.
__device__ __forceinline__ void write_h(char *sH, const float *__restrict__ bias,
                                        int lr, int lg, f32x4 (&acc)[8]) {
#pragma unroll
  for (int nt = 0; nt < 8; ++nt) {
    int c = nt * 16 + lr;
    float bv = bias[c];
#pragma unroll
    for (int j = 0; j < 4; ++j) {
      float h = fmaxf(acc[nt][j] + bv, 0.0f);
      unsigned hb = rne_bf16(h);
      float fh = __builtin_bit_cast(float, hb << 16);
      unsigned lb = rne_bf16(h - fh);
      int hr   = lg * 4 + j;
      int boff = hr * 256 + (((c >> 3) ^ (hr & 7)) << 4) + (c & 7) * 2;
      *(short *)(sH + boff)        = (short)hb;
      *(short *)(sH + 4096 + boff) = (short)lb;
    }
  }
}

// Convert W0[384,128], W1[128,128], W2[128,128] fp32 -> transposed bf16 hi/lo
// planes in d_ws:  WT[n][k].  hi at off, lo at off+planeElems (shorts).
__global__ void prep_weights(const float *__restrict__ W0,
                             const float *__restrict__ W1,
                             const float *__restrict__ W2,
                             short *__restrict__ ws) {
  int idx = blockIdx.x * 256 + threadIdx.x;   // 81920 total
  const float *W;
  int K, off, rel, plane;
  if (idx < 49152)      { W = W0; K = 384; off = 0;      rel = idx;         plane = 49152; }
  else if (idx < 65536) { W = W1; K = 128; off = 98304;  rel = idx - 49152; plane = 16384; }
  else                  { W = W2; K = 128; off = 131072; rel = idx - 65536; plane = 16384; }
  int n = rel / K;
  int k = rel - n * K;
  float v = W[(size_t)k * 128 + n];
  unsigned hb = rne_bf16(v);
  float fh = __builtin_bit_cast(float, hb << 16);
  unsigned lb = rne_bf16(v - fh);
  ws[off + rel]         = (short)hb;
  ws[off + plane + rel] = (short)lb;
}

__global__ __launch_bounds__(512, 2) void edge_mlp(
    const float *__restrict__ sf, const float *__restrict__ rf,
    const float *__restrict__ ef, const int *__restrict__ snd,
    const int *__restrict__ rcv, const short *__restrict__ wt,
    const float *__restrict__ b0, const float *__restrict__ b1,
    const float *__restrict__ b2, const float *__restrict__ gamma,
    const float *__restrict__ beta, float *__restrict__ out) {
  __shared__ __align__(16) char lds[131072];  // 2x32K B dbuf + 8x8K h regions
  const int tid  = threadIdx.x;
  const int wave = tid >> 6;
  const int lane = tid & 63;
  const int lr   = lane & 15;   // A-row / B-col selector
  const int lg   = lane >> 4;   // k-group 0..3
  const int arow = blockIdx.x * 128 + wave * 16 + lr;  // edge this lane gathers
  const int sidx = snd[arow];
  const int ridx = rcv[arow];

  char *sB0 = lds;
  char *sB1 = lds + 32768;
  char *sH  = lds + 65536 + wave * 8192;  // wave-private [hi|lo][16][128]

  const f32x4 fz = {0.f, 0.f, 0.f, 0.f};
  f32x4 acc[8];
#pragma unroll
  for (int i = 0; i < 8; ++i) acc[i] = fz;

  // ---------------- layer 0: [128 x 384] @ W0 ----------------
  stage_slab(wt, 49152, 384, 0, sB0, tid);
  __syncthreads();
#pragma unroll
  for (int s = 0; s < 6; ++s) {
    const float *ab;
    if (s < 2)      ab = sf + (size_t)sidx * 128 + s * 64;        // sender
    else if (s < 4) ab = rf + (size_t)ridx * 128 + (s - 2) * 64;  // receiver
    else            ab = ef + (size_t)arow * 128 + (s - 4) * 64;  // edge feats
    float4 x0 = *(const float4 *)(ab + lg * 8);
    float4 x1 = *(const float4 *)(ab + lg * 8 + 4);
    float4 x2 = *(const float4 *)(ab + 32 + lg * 8);
    float4 x3 = *(const float4 *)(ab + 32 + lg * 8 + 4);
    if (s < 5) stage_slab(wt, 49152, 384, s + 1, (s & 1) ? sB0 : sB1, tid);
    const char *cur = (s & 1) ? sB1 : sB0;
    s16x8 ah, al;
    split8(x0, x1, ah, al);
    do_kstep(cur, lg, lr, ah, al, acc);
    split8(x2, x3, ah, al);
    do_kstep(cur, 4 + lg, lr, ah, al, acc);
    __syncthreads();
  }
  write_h(sH, b0, lr, lg, acc);

  // ---------------- layer 1 ----------------
#pragma unroll
  for (int i = 0; i < 8; ++i) acc[i] = fz;
  stage_slab(wt + 98304, 16384, 128, 0, sB0, tid);
  __syncthreads();
#pragma unroll
  for (int s = 0; s < 2; ++s) {
    if (s < 1) stage_slab(wt + 98304, 16384, 128, 1, sB1, tid);
    const char *cur = (s & 1) ? sB1 : sB0;
#pragma unroll
    for (int ks = 0; ks < 2; ++ks) {
      int kch  = s * 8 + ks * 4 + lg;                       // 16B col in h row
      int aoff = lr * 256 + ((kch ^ (lr & 7)) << 4);
      s16x8 ah = *(const s16x8 *)(sH + aoff);
      s16x8 al = *(const s16x8 *)(sH + 4096 + aoff);
      do_kstep(cur, ks * 4 + lg, lr, ah, al, acc);
    }
    __syncthreads();
  }
  write_h(sH, b1, lr, lg, acc);

  // ---------------- layer 2 ----------------
#pragma unroll
  for (int i = 0; i < 8; ++i) acc[i] = fz;
  stage_slab(wt + 131072, 16384, 128, 0, sB0, tid);
  __syncthreads();
#pragma unroll
  for (int s = 0; s < 2; ++s) {
    if (s < 1) stage_slab(wt + 131072, 16384, 128, 1, sB1, tid);
    const char *cur = (s & 1) ? sB1 : sB0;
#pragma unroll
    for (int ks = 0; ks < 2; ++ks) {
      int kch  = s * 8 + ks * 4 + lg;
      int aoff = lr * 256 + ((kch ^ (lr & 7)) << 4);
      s16x8 ah = *(const s16x8 *)(sH + aoff);
      s16x8 al = *(const s16x8 *)(sH + 4096 + aoff);
      do_kstep(cur, ks * 4 + lg, lr, ah, al, acc);
    }
    __syncthreads();
  }

  // ---------------- bias + LayerNorm + store ----------------
  float hv[8][4];
  float sum[4] = {0.f, 0.f, 0.f, 0.f}, sq[4] = {0.f, 0.f, 0.f, 0.f};
#pragma unroll
  for (int nt = 0; nt < 8; ++nt) {
    int c = nt * 16 + lr;
    float bv = b2[c];
#pragma unroll
    for (int j = 0; j < 4; ++j) {
      float v = acc[nt][j] + bv;
      hv[nt][j] = v;
      sum[j] += v;
      sq[j]  += v * v;
    }
  }
#pragma unroll
  for (int m = 1; m < 16; m <<= 1) {   // reduce across the 16 col-lanes
#pragma unroll
    for (int j = 0; j < 4; ++j) {
      sum[j] += __shfl_xor(sum[j], m, 64);
      sq[j]  += __shfl_xor(sq[j], m, 64);
    }
  }
  float mu[4], rs[4];
#pragma unroll
  for (int j = 0; j < 4; ++j) {
    mu[j] = sum[j] * (1.0f / 128.0f);
    float var = sq[j] * (1.0f / 128.0f) - mu[j] * mu[j];
    rs[j] = rsqrtf(var + 1e-3f);
  }
  const int orow = blockIdx.x * 128 + wave * 16 + lg * 4;  // output rows
#pragma unroll
  for (int nt = 0; nt < 8; ++nt) {
    int c = nt * 16 + lr;
    float g  = gamma[c];
    float bt = beta[c];
#pragma unroll
    for (int j = 0; j < 4; ++j) {
      out[(size_t)(orow + j) * 128 + c] = (hv[nt][j] - mu[j]) * rs[j] * g + bt;
    }
  }
}

extern "C" void kernel_launch(void* const* d_in, const int* in_sizes, int n_in,
                              void* d_out, int out_size, void* d_ws, size_t ws_size,
                              hipStream_t stream) {
  const float *sf    = (const float *)d_in[0];
  const float *rf    = (const float *)d_in[1];
  const float *ef    = (const float *)d_in[2];
  const int   *snd   = (const int *)d_in[3];
  const int   *rcv   = (const int *)d_in[4];
  const float *W0    = (const float *)d_in[5];
  const float *b0    = (const float *)d_in[6];
  const float *W1    = (const float *)d_in[7];
  const float *b1    = (const float *)d_in[8];
  const float *W2    = (const float *)d_in[9];
  const float *b2    = (const float *)d_in[10];
  const float *gamma = (const float *)d_in[11];
  const float *beta  = (const float *)d_in[12];
  short *wt = (short *)d_ws;  // 163840 shorts = 320 KB, rebuilt every launch

  prep_weights<<<320, 256, 0, stream>>>(W0, W1, W2, wt);
  edge_mlp<<<2500, 512, 0, stream>>>(sf, rf, ef, snd, rcv, wt,
                                     b0, b1, b2, gamma, beta, (float *)d_out);
}

// Round 2
// 426.173 us; speedup vs baseline: 1.1692x; 1.1692x over previous
//
#include <hip/hip_runtime.h>
#include <stdint.h>

// ---------------------------------------------------------------------------
// MeshGraphNets edge processor, round 2.
//   gather+concat(384) -> 128 relu -> 128 relu -> 128 -> LayerNorm, E=320000.
//
// Design:
//  * Swapped MFMA orientation: D'[n][e] = W^T[n][k] * x^T[k][e] with
//    v_mfma_f32_32x32x16_f16.  Each lane keeps ITS edge (col = lane&31)
//    through all three layers -> zero LDS for activations.
//  * k-axis of W1/W2 pre-permuted by pi = swap(bit2,bit3) so each output
//    tile's accumulator registers [8*(ks&1) .. +8) ARE the next layer's
//    B-fragments. Layer transitions = bias+relu+cvt_f16 in-register.
//  * Single-plane fp16 (err ~3e-4/layer, vs observed 0.0156 absmax).
//  * Weights: prep kernel writes a pre-swizzled fp16 image (slab=16KB) to
//    d_ws; edge kernel stages slabs with global_load_lds (16B) into a
//    4-deep LDS ring (64KB total) -> 2 blocks/CU, 4 waves/SIMD.
//  * LDS read swizzle: 16B-chunk slot = kc ^ (n&7)  (G4 st-style XOR).
// ---------------------------------------------------------------------------

typedef __attribute__((ext_vector_type(8)))  short    s16x8;
typedef __attribute__((ext_vector_type(8)))  _Float16 f16x8;
typedef __attribute__((ext_vector_type(16))) float    f32x16;
typedef __attribute__((ext_vector_type(4)))  float    f32x4;

__device__ __forceinline__ f32x16 mfma16(f16x8 a, f16x8 b, f32x16 c) {
  return __builtin_amdgcn_mfma_f32_32x32x16_f16(a, b, c, 0, 0, 0);
}

// ---------------------------------------------------------------------------
// prep: W0[384][128], W1[128][128], W2[128][128] (fp32, k-major) ->
// fp16 transposed swizzled slab images in d_ws.
// Image (shorts): slab*8192 + n*64 + ((kc ^ (n&7))*8) + j
//   where slot k = slab*64 + kc*8 + j ; for W1/W2 the source row is
//   k_true = swap23(k_slot)  (pi is an involution).
// W0 at short-offset 0 (6 slabs), W1 at 49152 (2), W2 at 65536 (2).
// ---------------------------------------------------------------------------
__global__ void prep_weights(const float* __restrict__ W0,
                             const float* __restrict__ W1,
                             const float* __restrict__ W2,
                             short* __restrict__ ws) {
  int tid = blockIdx.x * 256 + threadIdx.x;        // 10240 threads
  const float* W;
  int rel, imgbase, perm;
  if (tid < 6144)      { W = W0; rel = tid;        imgbase = 0;     perm = 0; }
  else if (tid < 8192) { W = W1; rel = tid - 6144; imgbase = 49152; perm = 1; }
  else                 { W = W2; rel = tid - 8192; imgbase = 65536; perm = 1; }
  int n     = rel & 127;
  int chunk = rel >> 7;       // slab*8 + kc
  int slab  = chunk >> 3;
  int kc    = chunk & 7;
  s16x8 o;
#pragma unroll
  for (int j = 0; j < 8; ++j) {
    int kslot = slab * 64 + kc * 8 + j;
    int ktrue = perm ? ((kslot & ~12) | ((kslot & 4) << 1) | ((kslot & 8) >> 1))
                     : kslot;
    float v = W[(size_t)ktrue * 128 + n];
    o[j] = __builtin_bit_cast(short, (_Float16)v);
  }
  *(s16x8*)(ws + imgbase + slab * 8192 + n * 64 + ((kc ^ (n & 7)) << 3)) = o;
}

// Stage slab s (16KB) from the ws image into LDS ring slot s&3 via
// global_load_lds: linear dest (base + lane*16), identity copy of the
// pre-swizzled image.  2 insts/thread.
__device__ __forceinline__ void stage(const short* __restrict__ ws, int s,
                                      char* lds, int tid) {
  char* buf = lds + (s & 3) * 16384;
  const char* g = (const char*)ws + s * 16384;
#pragma unroll
  for (int i = 0; i < 2; ++i) {
    char* lp = buf + (i * 512 + (tid & ~63)) * 16;   // wave-uniform base
    const char* gp = g + (i * 512 + tid) * 16;       // per-lane source
    __builtin_amdgcn_global_load_lds(
        (__attribute__((address_space(1))) const void*)gp,
        (__attribute__((address_space(3))) void*)lp, 16, 0, 0);
  }
}

// One K=16 step: 4 output tiles, A = W^T fragment from swizzled LDS,
// B = xf (lane-resident activations).
__device__ __forceinline__ void kstep(const char* buf, int q, int lg1,
                                      int e31, f16x8 xf, f32x16* acc) {
  const int kc = q * 2 + lg1;
  const int slot = (kc ^ (e31 & 7)) << 4;
#pragma unroll
  for (int nt = 0; nt < 4; ++nt) {
    int n = nt * 32 + e31;
    s16x8 wf = *(const s16x8*)(buf + n * 128 + slot);
    acc[nt] = mfma16(__builtin_bit_cast(f16x8, wf), xf, acc[nt]);
  }
}

// bias + relu + cvt to fp16 B-fragments.  Accumulator element (nt, reg)
// holds n = nt*32 + (reg&3) + 8*(reg>>2) + 4*lg1; fragment fr[ks] takes
// regs [8*(ks&1) .. +8) of tile ks>>1 (this IS pi's consumption order).
__device__ __forceinline__ void transition(const float* __restrict__ b,
                                           int lg1, f32x16* acc, f16x8* fr) {
#pragma unroll
  for (int ks = 0; ks < 8; ++ks) {
    const int nt = ks >> 1;
#pragma unroll
    for (int jq = 0; jq < 2; ++jq) {
      int nb = nt * 32 + 16 * (ks & 1) + 8 * jq + 4 * lg1;
      f32x4 bv = *(const f32x4*)(b + nb);
#pragma unroll
      for (int r = 0; r < 4; ++r) {
        float h = acc[nt][8 * (ks & 1) + jq * 4 + r] + bv[r];
        fr[ks][jq * 4 + r] = (_Float16)fmaxf(h, 0.0f);
      }
    }
  }
}

__device__ __forceinline__ void zero_acc(f32x16* acc) {
#pragma unroll
  for (int nt = 0; nt < 4; ++nt)
#pragma unroll
    for (int i = 0; i < 16; ++i) acc[nt][i] = 0.0f;
}

__global__ __launch_bounds__(512, 4) void edge_mlp(
    const float* __restrict__ sf, const float* __restrict__ rf,
    const float* __restrict__ ef, const int* __restrict__ snd,
    const int* __restrict__ rcv, const short* __restrict__ wt,
    const float* __restrict__ b0, const float* __restrict__ b1,
    const float* __restrict__ b2, const float* __restrict__ gamma,
    const float* __restrict__ beta, float* __restrict__ out) {
  __shared__ __align__(16) char lds[65536];          // 4 x 16KB ring
  const int tid = threadIdx.x;
  const int w   = tid >> 6;
  const int lane = tid & 63;
  const int e31 = lane & 31;                         // this lane's edge slot
  const int lg1 = lane >> 5;                         // k-half
  const int e   = blockIdx.x * 256 + w * 32 + e31;   // 256 edges/block
  const int sidx = snd[e];
  const int ridx = rcv[e];

  // x source for global K-step t (t = 0..23, 16 features each)
  const float* xbase0 = sf + (size_t)sidx * 128 + lg1 * 8;
  const float* xbase1 = rf + (size_t)ridx * 128 + lg1 * 8;
  const float* xbase2 = ef + (size_t)e    * 128 + lg1 * 8;

#define XPTR(t) ((t) < 8 ? xbase0 + (t) * 16 \
                : (t) < 16 ? xbase1 + ((t) - 8) * 16 \
                : xbase2 + ((t) - 16) * 16)

  f32x16 acc[4];
  zero_acc(acc);
  f32x4 xa[24], xb[24];

  // prologue: stage slabs 0,1 ; prefetch x for t=0,1
  stage(wt, 0, lds, tid);
  stage(wt, 1, lds, tid);
  { const float* p0 = XPTR(0); xa[0] = *(const f32x4*)p0; xb[0] = *(const f32x4*)(p0 + 4);
    const float* p1 = XPTR(1); xa[1] = *(const f32x4*)p1; xb[1] = *(const f32x4*)(p1 + 4); }
  __syncthreads();

  // ------------- layer 0: slabs 0..5 (stages 2..7 = W0 tail + W1) -------------
#pragma unroll
  for (int s = 0; s < 6; ++s) {
    stage(wt, s + 2, lds, tid);
    const char* buf = lds + (s & 3) * 16384;
#pragma unroll
    for (int q = 0; q < 4; ++q) {
      const int t = s * 4 + q;
      if (t + 2 < 24) {               // rolling 2-kstep-ahead x prefetch
        const float* p = XPTR(t + 2);
        xa[t + 2] = *(const f32x4*)p;
        xb[t + 2] = *(const f32x4*)(p + 4);
      }
      f16x8 xf;
#pragma unroll
      for (int j = 0; j < 4; ++j) {
        xf[j]     = (_Float16)xa[t][j];
        xf[4 + j] = (_Float16)xb[t][j];
      }
      kstep(buf, q, lg1, e31, xf, acc);
    }
    __syncthreads();
  }

  f16x8 fr[8];
  transition(b0, lg1, acc, fr);
  zero_acc(acc);

  // ------------- layer 1: slabs 6,7 (stages 8,9 = W2) -------------
#pragma unroll
  for (int s = 6; s < 8; ++s) {
    stage(wt, s + 2, lds, tid);
    const char* buf = lds + (s & 3) * 16384;
#pragma unroll
    for (int q = 0; q < 4; ++q) kstep(buf, q, lg1, e31, fr[(s - 6) * 4 + q], acc);
    __syncthreads();
  }

  transition(b1, lg1, acc, fr);
  zero_acc(acc);

  // ------------- layer 2: slabs 8,9 (no staging, no barriers) -------------
#pragma unroll
  for (int s = 8; s < 10; ++s) {
    const char* buf = lds + (s & 3) * 16384;
#pragma unroll
    for (int q = 0; q < 4; ++q) kstep(buf, q, lg1, e31, fr[(s - 8) * 4 + q], acc);
  }

  // ------------- bias + LayerNorm + store -------------
  float sum = 0.0f, sq = 0.0f;
#pragma unroll
  for (int nt = 0; nt < 4; ++nt)
#pragma unroll
    for (int qq = 0; qq < 4; ++qq) {
      int nb = nt * 32 + qq * 8 + 4 * lg1;
      f32x4 bv = *(const f32x4*)(b2 + nb);
#pragma unroll
      for (int r = 0; r < 4; ++r) {
        float v = acc[nt][qq * 4 + r] + bv[r];
        acc[nt][qq * 4 + r] = v;
        sum += v;
        sq  += v * v;
      }
    }
  sum += __shfl_xor(sum, 32, 64);     // partner lane holds the other 64 of 128
  sq  += __shfl_xor(sq, 32, 64);
  const float mu  = sum * (1.0f / 128.0f);
  const float var = sq * (1.0f / 128.0f) - mu * mu;
  const float rs  = rsqrtf(var + 1e-3f);

  float* op = out + (size_t)e * 128;
#pragma unroll
  for (int nt = 0; nt < 4; ++nt)
#pragma unroll
    for (int qq = 0; qq < 4; ++qq) {
      int nb = nt * 32 + qq * 8 + 4 * lg1;
      f32x4 g  = *(const f32x4*)(gamma + nb);
      f32x4 bt = *(const f32x4*)(beta + nb);
      f32x4 o;
#pragma unroll
      for (int r = 0; r < 4; ++r)
        o[r] = (acc[nt][qq * 4 + r] - mu) * rs * g[r] + bt[r];
      *(f32x4*)(op + nb) = o;
    }
#undef XPTR
}

extern "C" void kernel_launch(void* const* d_in, const int* in_sizes, int n_in,
                              void* d_out, int out_size, void* d_ws, size_t ws_size,
                              hipStream_t stream) {
  const float* sf    = (const float*)d_in[0];
  const float* rf    = (const float*)d_in[1];
  const float* ef    = (const float*)d_in[2];
  const int*   snd   = (const int*)d_in[3];
  const int*   rcv   = (const int*)d_in[4];
  const float* W0    = (const float*)d_in[5];
  const float* b0    = (const float*)d_in[6];
  const float* W1    = (const float*)d_in[7];
  const float* b1    = (const float*)d_in[8];
  const float* W2    = (const float*)d_in[9];
  const float* b2    = (const float*)d_in[10];
  const float* gamma = (const float*)d_in[11];
  const float* beta  = (const float*)d_in[12];
  short* wt = (short*)d_ws;   // 81920 shorts = 160KB swizzled fp16 image

  prep_weights<<<40, 256, 0, stream>>>(W0, W1, W2, wt);
  edge_mlp<<<1250, 512, 0, stream>>>(sf, rf, ef, snd, rcv, wt,
                                     b0, b1, b2, gamma, beta, (float*)d_out);
}